// Round 4
// baseline (378.105 us; speedup 1.0000x reference)
//
#include <hip/hip_runtime.h>

#define IN_C 128
#define OUT_CH 128

// ---------------- CSR build ----------------

__global__ void k_count(const int* __restrict__ dst, int* __restrict__ cnt, int E) {
    int e = blockIdx.x * blockDim.x + threadIdx.x;
    if (e < E) atomicAdd(&cnt[dst[e]], 1);
}

// single-block exclusive scan over n counts (n ~ 50000): 1024 threads, chunked
__global__ void k_scan(const int* __restrict__ cnt, int* __restrict__ offs, int n) {
    __shared__ int buf[1024];
    __shared__ int carry_s;
    if (threadIdx.x == 0) carry_s = 0;
    __syncthreads();
    for (int base = 0; base < n; base += 1024) {
        int i = base + (int)threadIdx.x;
        int v = (i < n) ? cnt[i] : 0;
        buf[threadIdx.x] = v;
        __syncthreads();
        for (int d = 1; d < 1024; d <<= 1) {
            int t = (threadIdx.x >= (unsigned)d) ? buf[threadIdx.x - d] : 0;
            __syncthreads();
            buf[threadIdx.x] += t;
            __syncthreads();
        }
        int inc = buf[threadIdx.x];
        int carry = carry_s;
        __syncthreads();                 // everyone reads carry_s before 1023 updates it
        if (i < n) offs[i] = carry + inc - v;   // exclusive
        if (threadIdx.x == 1023) carry_s = carry + inc;
        __syncthreads();
    }
    if (threadIdx.x == 0) offs[n] = carry_s;
}

__global__ void k_bucket(const int* __restrict__ src, const int* __restrict__ dst,
                         const int* __restrict__ offs, int* __restrict__ cursor,
                         int* __restrict__ ebuf, int E) {
    int e = blockIdx.x * blockDim.x + threadIdx.x;
    if (e < E) {
        int d = dst[e];
        int pos = offs[d] + atomicAdd(&cursor[d], 1);
        ebuf[pos] = src[e];
    }
}

// ---------------- fused aggregate + 2x linear + bias + L2 norm ----------------
// Block = 256 threads (4 waves), 32 nodes per block.
// Phase 1: each wave aggregates 8 nodes (mean of neighbor rows) + stages root x into LDS.
// Phase 2: thread t computes output channel o=t&127 for 16 nodes (g=t>>7).
// Phase 3: cross-thread sum-of-squares reduce -> normalize -> coalesced store.
__global__ __launch_bounds__(256) void k_sage(
        const float* __restrict__ x, const int* __restrict__ ebuf,
        const int* __restrict__ offs, const int* __restrict__ cnt,
        const float* __restrict__ Wl, const float* __restrict__ bl,
        const float* __restrict__ Wr, float* __restrict__ out, int N) {
    __shared__ float feat[32][256];   // [node][0..127]=mean, [128..255]=root x  (32 KiB)
    __shared__ float red[4][16];

    const int tid  = threadIdx.x;
    const int lane = tid & 63;
    const int wv   = tid >> 6;
    const int node0 = blockIdx.x * 32;

    // ---- phase 1: neighbor mean + root staging ----
    for (int q = 0; q < 8; ++q) {
        const int nl   = wv * 8 + q;
        const int node = node0 + nl;
        float2 a  = make_float2(0.f, 0.f);
        float2 xo = make_float2(0.f, 0.f);
        if (node < N) {
            const int off = offs[node];
            const int m   = cnt[node];
            for (int j = 0; j < m; j += 64) {
                int eid = 0;
                if (j + lane < m) eid = ebuf[off + j + lane];
                const int kmax = min(64, m - j);
                for (int kk = 0; kk < kmax; ++kk) {
                    const int s = __shfl(eid, kk);
                    const float2 xr = *reinterpret_cast<const float2*>(
                        x + (size_t)s * IN_C + lane * 2);
                    a.x += xr.x; a.y += xr.y;
                }
            }
            const float inv = 1.0f / fmaxf((float)m, 1.0f);
            a.x *= inv; a.y *= inv;
            xo = *reinterpret_cast<const float2*>(x + (size_t)node * IN_C + lane * 2);
        }
        feat[nl][lane * 2 + 0]       = a.x;
        feat[nl][lane * 2 + 1]       = a.y;
        feat[nl][128 + lane * 2 + 0] = xo.x;
        feat[nl][128 + lane * 2 + 1] = xo.y;
    }
    __syncthreads();

    // ---- phase 2: out[n][o] = Wl[o,:]·mean[n] + Wr[o,:]·x[n] ----
    const int o = tid & 127;
    const int g = tid >> 7;   // 0: nodes 0..15, 1: nodes 16..31
    float acc[16];
#pragma unroll
    for (int n = 0; n < 16; ++n) acc[n] = 0.f;
    const float* wl = Wl + (size_t)o * IN_C;
    const float* wr = Wr + (size_t)o * IN_C;
    for (int c = 0; c < IN_C; c += 4) {
        const float4 av = *reinterpret_cast<const float4*>(wl + c);
        const float4 bv = *reinterpret_cast<const float4*>(wr + c);
#pragma unroll
        for (int n = 0; n < 16; ++n) {
            const float* f = &feat[g * 16 + n][0];
            const float4 mv = *reinterpret_cast<const float4*>(f + c);        // LDS broadcast
            const float4 xv = *reinterpret_cast<const float4*>(f + 128 + c);  // LDS broadcast
            acc[n] += av.x * mv.x + av.y * mv.y + av.z * mv.z + av.w * mv.w;
            acc[n] += bv.x * xv.x + bv.y * xv.y + bv.z * xv.z + bv.w * xv.w;
        }
    }
    const float bias = bl[o];
#pragma unroll
    for (int n = 0; n < 16; ++n) acc[n] += bias;

    // ---- phase 3: row L2 norm across the 128 threads owning this node ----
#pragma unroll
    for (int n = 0; n < 16; ++n) {
        float v = acc[n] * acc[n];
        for (int d = 1; d < 64; d <<= 1) v += __shfl_xor(v, d);
        if (lane == 0) red[wv][n] = v;
    }
    __syncthreads();
#pragma unroll
    for (int n = 0; n < 16; ++n) {
        const int node = node0 + g * 16 + n;
        if (node < N) {
            const float ss = red[g * 2 + 0][n] + red[g * 2 + 1][n];
            const float rn = 1.0f / fmaxf(sqrtf(ss), 1e-12f);
            out[(size_t)node * OUT_CH + o] = acc[n] * rn;
        }
    }
}

extern "C" void kernel_launch(void* const* d_in, const int* in_sizes, int n_in,
                              void* d_out, int out_size, void* d_ws, size_t ws_size,
                              hipStream_t stream) {
    const float* x    = (const float*)d_in[0];
    const int*   edge = (const int*)d_in[1];   // [2, E] int32 (harness canonicalizes ints)
    const float* Wl   = (const float*)d_in[2];
    const float* bl   = (const float*)d_in[3];
    const float* Wr   = (const float*)d_in[4];
    float*       out  = (float*)d_out;

    const int N = in_sizes[0] / IN_C;
    const int E = in_sizes[1] / 2;
    const int* src = edge;
    const int* dst = edge + E;

    // workspace layout: cnt[N] | offs[N+1] | cursor[N] | ebuf[E]  (~3.8 MB)
    int* ws     = (int*)d_ws;
    int* cnt    = ws;
    int* offs   = cnt + N;
    int* cursor = offs + N + 1;
    int* ebuf   = cursor + N;

    hipMemsetAsync(d_ws, 0, (size_t)(3 * N + 1) * sizeof(int), stream);

    const int blocksE = (E + 255) / 256;
    k_count <<<blocksE, 256, 0, stream>>>(dst, cnt, E);
    k_scan  <<<1, 1024, 0, stream>>>(cnt, offs, N);
    k_bucket<<<blocksE, 256, 0, stream>>>(src, dst, offs, cursor, ebuf, E);

    const int blocksN = (N + 31) / 32;
    k_sage  <<<blocksN, 256, 0, stream>>>(x, ebuf, offs, cnt, Wl, bl, Wr, out, N);
}

// Round 5
// 170.694 us; speedup vs baseline: 2.2151x; 2.2151x over previous
//
#include <hip/hip_runtime.h>
#include <hip/hip_bf16.h>

#define IN_C 128
#define OUT_CH 128

typedef __attribute__((ext_vector_type(8))) short bf16x8;   // 8 bf16 = 4 VGPRs
typedef __attribute__((ext_vector_type(4))) float f32x4;

__device__ __forceinline__ unsigned pk2(float a, float b) {
    union { __hip_bfloat162 h; unsigned u; } c;
    c.h = __float22bfloat162_rn(make_float2(a, b));
    return c.u;
}
__device__ __forceinline__ float blo(unsigned v) { return __uint_as_float(v << 16); }
__device__ __forceinline__ float bhi(unsigned v) { return __uint_as_float(v & 0xffff0000u); }

// ---------------- prep: bf16 copies ----------------

__global__ void k_prep_x(const float* __restrict__ x, uint* __restrict__ xb, int total8) {
    int i = blockIdx.x * blockDim.x + threadIdx.x;
    if (i < total8) {
        const float4* p = reinterpret_cast<const float4*>(x + (size_t)i * 8);
        float4 v0 = p[0], v1 = p[1];
        uint4 o;
        o.x = pk2(v0.x, v0.y); o.y = pk2(v0.z, v0.w);
        o.z = pk2(v1.x, v1.y); o.w = pk2(v1.z, v1.w);
        reinterpret_cast<uint4*>(xb)[i] = o;
    }
}

// Wcat[n][k] bf16, k<128 -> Wl[n][k], k>=128 -> Wr[n][k-128]
__global__ void k_prep_w(const float* __restrict__ Wl, const float* __restrict__ Wr,
                         unsigned short* __restrict__ Wcat) {
    int idx = blockIdx.x * blockDim.x + threadIdx.x;   // 128*256
    int n = idx >> 8, k = idx & 255;
    float v = (k < IN_C) ? Wl[n * IN_C + k] : Wr[n * IN_C + (k - IN_C)];
    union { __hip_bfloat16 h; unsigned short s; } c;
    c.h = __float2bfloat16(v);
    Wcat[idx] = c.s;
}

// ---------------- CSR build ----------------

__global__ void k_count_pos(const int* __restrict__ dst, int* __restrict__ cnt,
                            int* __restrict__ pos, int E) {
    int e = blockIdx.x * blockDim.x + threadIdx.x;
    if (e < E) pos[e] = atomicAdd(&cnt[dst[e]], 1);
}

__global__ void k_bsum(const int* __restrict__ cnt, int* __restrict__ bsum, int N) {
    int i = blockIdx.x * 256 + threadIdx.x;
    int v = (i < N) ? cnt[i] : 0;
    for (int d = 1; d < 64; d <<= 1) v += __shfl_xor(v, d);
    __shared__ int w4[4];
    if ((threadIdx.x & 63) == 0) w4[threadIdx.x >> 6] = v;
    __syncthreads();
    if (threadIdx.x == 0) bsum[blockIdx.x] = w4[0] + w4[1] + w4[2] + w4[3];
}

__global__ void k_bscan(int* __restrict__ bsum, int nb) {   // nb <= 256
    __shared__ int b[256];
    int t = threadIdx.x;
    int v = (t < nb) ? bsum[t] : 0;
    b[t] = v; __syncthreads();
    for (int d = 1; d < 256; d <<= 1) {
        int u = (t >= d) ? b[t - d] : 0;
        __syncthreads();
        b[t] += u;
        __syncthreads();
    }
    if (t < nb) bsum[t] = b[t] - v;   // exclusive
}

__global__ void k_offs(const int* __restrict__ cnt, const int* __restrict__ bsum,
                       int* __restrict__ offs, int N) {
    __shared__ int b[256];
    int t = threadIdx.x, i = blockIdx.x * 256 + t;
    int v = (i < N) ? cnt[i] : 0;
    b[t] = v; __syncthreads();
    for (int d = 1; d < 256; d <<= 1) {
        int u = (t >= d) ? b[t - d] : 0;
        __syncthreads();
        b[t] += u;
        __syncthreads();
    }
    if (i < N) offs[i] = bsum[blockIdx.x] + b[t] - v;
}

__global__ void k_bucket(const int* __restrict__ src, const int* __restrict__ dst,
                         const int* __restrict__ pos, const int* __restrict__ offs,
                         int* __restrict__ ebuf, int E) {
    int e = blockIdx.x * blockDim.x + threadIdx.x;
    if (e < E) ebuf[offs[dst[e]] + pos[e]] = src[e];
}

// ---------------- fused gather-mean + MFMA GEMM + bias + L2 norm ----------------
// Block = 256 threads (4 waves), 32 nodes.
// Gather: wave wv aggregates nodes wv*8..+7; 2 edges/iter (lane halves), bf16 rows (256 B).
// LDS feat[32][264] bf16: k 0..127 = mean, 128..255 = root x. +8 pad -> bank-uniform b128 reads.
// GEMM: [mean|x](32x256) @ Wcat^T(256x128) via mfma_f32_16x16x32_bf16.
//   wave (ng=wv&1, cg=wv>>1): nodes ng*16..+15, cols cg*64..+63. 8 K-steps x 4 N-frags.
// Epilogue: bias, cross-lane + cross-wave sum-of-squares, normalize, store fp32.
template<bool BF16X>
__global__ __launch_bounds__(256) void k_sage(
        const float* __restrict__ x, const uint* __restrict__ xb,
        const int* __restrict__ ebuf, const int* __restrict__ offs,
        const int* __restrict__ cnt, const unsigned short* __restrict__ Wcat,
        const float* __restrict__ bl, float* __restrict__ out, int N) {
    __shared__ unsigned short feat[32][264];
    __shared__ float ssh[2][32];

    const int tid  = threadIdx.x;
    const int lane = tid & 63;
    const int wv   = tid >> 6;
    const int node0 = blockIdx.x * 32;

    // ---- gather phase ----
    for (int q = 0; q < 8; ++q) {
        const int nl   = wv * 8 + q;
        const int node = node0 + nl;
        float4 a = make_float4(0.f, 0.f, 0.f, 0.f);
        if (node < N) {
            const int off = offs[node];
            const int m   = cnt[node];
            for (int j = 0; j < m; j += 64) {
                int eid = (j + lane < m) ? ebuf[off + j + lane] : 0;
                const int kmax = min(64, m - j);
                int kk = 0;
                for (; kk + 1 < kmax; kk += 2) {
                    const int s0 = __shfl(eid, kk);
                    const int s1 = __shfl(eid, kk + 1);
                    const int s  = (lane < 32) ? s0 : s1;
                    if (BF16X) {
                        const uint2 v = *reinterpret_cast<const uint2*>(
                            xb + (size_t)s * 64 + (lane & 31) * 2);
                        a.x += blo(v.x); a.y += bhi(v.x);
                        a.z += blo(v.y); a.w += bhi(v.y);
                    } else {
                        const float4 v = *reinterpret_cast<const float4*>(
                            x + (size_t)s * IN_C + (lane & 31) * 4);
                        a.x += v.x; a.y += v.y; a.z += v.z; a.w += v.w;
                    }
                }
                if (kk < kmax) {     // odd tail: lanes<32 only
                    const int s0 = __shfl(eid, kk);
                    if (lane < 32) {
                        if (BF16X) {
                            const uint2 v = *reinterpret_cast<const uint2*>(
                                xb + (size_t)s0 * 64 + (lane & 31) * 2);
                            a.x += blo(v.x); a.y += bhi(v.x);
                            a.z += blo(v.y); a.w += bhi(v.y);
                        } else {
                            const float4 v = *reinterpret_cast<const float4*>(
                                x + (size_t)s0 * IN_C + (lane & 31) * 4);
                            a.x += v.x; a.y += v.y; a.z += v.z; a.w += v.w;
                        }
                    }
                }
            }
            // combine lane halves
            a.x += __shfl_xor(a.x, 32);
            a.y += __shfl_xor(a.y, 32);
            a.z += __shfl_xor(a.z, 32);
            a.w += __shfl_xor(a.w, 32);
            const float inv = 1.0f / fmaxf((float)m, 1.0f);
            a.x *= inv; a.y *= inv; a.z *= inv; a.w *= inv;
        }
        unsigned short* frow = &feat[nl][0];
        if (lane < 32) {
            uint2 pw; pw.x = pk2(a.x, a.y); pw.y = pk2(a.z, a.w);
            *reinterpret_cast<uint2*>(reinterpret_cast<char*>(frow) + lane * 8) = pw;
        }
        unsigned xr = 0;
        if (node < N) {
            if (BF16X) xr = xb[(size_t)node * 64 + lane];
            else {
                const float2 t = *reinterpret_cast<const float2*>(
                    x + (size_t)node * IN_C + lane * 2);
                xr = pk2(t.x, t.y);
            }
        }
        *reinterpret_cast<unsigned*>(reinterpret_cast<char*>(frow) + 256 + lane * 4) = xr;
    }
    __syncthreads();

    // ---- MFMA phase ----
    const int ng = wv & 1;        // node half
    const int cg = wv >> 1;       // column half (64 cols)
    const int m_lane = lane & 15;
    const int kq = lane >> 4;     // k-quarter
    f32x4 acc[4] = {{0,0,0,0},{0,0,0,0},{0,0,0,0},{0,0,0,0}};

    const char* arow = reinterpret_cast<const char*>(&feat[ng * 16 + m_lane][0]) + kq * 16;
    const char* bbase = reinterpret_cast<const char*>(Wcat) + kq * 16;
#pragma unroll
    for (int ks = 0; ks < 8; ++ks) {
        const bf16x8 af = *reinterpret_cast<const bf16x8*>(arow + ks * 64);
#pragma unroll
        for (int nf = 0; nf < 4; ++nf) {
            const int n = cg * 64 + nf * 16 + m_lane;
            const bf16x8 bfr = *reinterpret_cast<const bf16x8*>(bbase + (size_t)n * 512 + ks * 64);
            acc[nf] = __builtin_amdgcn_mfma_f32_16x16x32_bf16(af, bfr, acc[nf], 0, 0, 0);
        }
    }

    // bias
#pragma unroll
    for (int nf = 0; nf < 4; ++nf) {
        const float bb = bl[cg * 64 + nf * 16 + m_lane];
        acc[nf][0] += bb; acc[nf][1] += bb; acc[nf][2] += bb; acc[nf][3] += bb;
    }

    // sum of squares: reduce over 16 cols in-wave, then over the 2 col-halves via LDS
#pragma unroll
    for (int r = 0; r < 4; ++r) {
        float v = acc[0][r]*acc[0][r] + acc[1][r]*acc[1][r]
                + acc[2][r]*acc[2][r] + acc[3][r]*acc[3][r];
#pragma unroll
        for (int d = 1; d < 16; d <<= 1) v += __shfl_xor(v, d);
        if (m_lane == 0) ssh[cg][ng * 16 + kq * 4 + r] = v;
    }
    __syncthreads();

#pragma unroll
    for (int r = 0; r < 4; ++r) {
        const int nl = ng * 16 + kq * 4 + r;
        const int node = node0 + nl;
        if (node < N) {
            const float ss = ssh[0][nl] + ssh[1][nl];
            const float rn = 1.0f / fmaxf(sqrtf(ss), 1e-12f);
#pragma unroll
            for (int nf = 0; nf < 4; ++nf)
                out[(size_t)node * OUT_CH + cg * 64 + nf * 16 + m_lane] = acc[nf][r] * rn;
        }
    }
}

extern "C" void kernel_launch(void* const* d_in, const int* in_sizes, int n_in,
                              void* d_out, int out_size, void* d_ws, size_t ws_size,
                              hipStream_t stream) {
    const float* x    = (const float*)d_in[0];
    const int*   edge = (const int*)d_in[1];
    const float* Wl   = (const float*)d_in[2];
    const float* bl   = (const float*)d_in[3];
    const float* Wr   = (const float*)d_in[4];
    float*       out  = (float*)d_out;

    const int N = in_sizes[0] / IN_C;
    const int E = in_sizes[1] / 2;
    const int* src = edge;
    const int* dst = edge + E;

    // ws layout: cnt[N] | offs[N] | bsum[256] | pos[E] | ebuf[E] | Wcat[128*256 bf16] | xb[N*128 bf16]
    char* p = (char*)d_ws;
    int* cnt  = (int*)p;            p += (size_t)N * 4;
    int* offs = (int*)p;            p += (size_t)N * 4;
    int* bsum = (int*)p;            p += 256 * 4;
    int* pos  = (int*)p;            p += (size_t)E * 4;
    int* ebuf = (int*)p;            p += (size_t)E * 4;
    unsigned short* Wcat = (unsigned short*)p;  p += 128 * 256 * 2;
    const size_t base_bytes = (size_t)(p - (char*)d_ws);
    uint* xb = (uint*)p;
    const bool use_xb = ws_size >= base_bytes + (size_t)N * IN_C * 2;

    hipMemsetAsync(cnt, 0, (size_t)N * 4, stream);
    k_prep_w<<<(128 * 256) / 256, 256, 0, stream>>>(Wl, Wr, Wcat);
    if (use_xb) {
        const int t8 = N * IN_C / 8;
        k_prep_x<<<(t8 + 255) / 256, 256, 0, stream>>>(x, xb, t8);
    }

    const int blocksE = (E + 255) / 256;
    const int nb = (N + 255) / 256;
    k_count_pos<<<blocksE, 256, 0, stream>>>(dst, cnt, pos, E);
    k_bsum  <<<nb, 256, 0, stream>>>(cnt, bsum, N);
    k_bscan <<<1, 256, 0, stream>>>(bsum, nb);
    k_offs  <<<nb, 256, 0, stream>>>(cnt, bsum, offs, N);
    k_bucket<<<blocksE, 256, 0, stream>>>(src, dst, pos, offs, ebuf, E);

    const int blocksN = (N + 31) / 32;
    if (use_xb)
        k_sage<true> <<<blocksN, 256, 0, stream>>>(x, xb, ebuf, offs, cnt, Wcat, bl, out, N);
    else
        k_sage<false><<<blocksN, 256, 0, stream>>>(x, xb, ebuf, offs, cnt, Wcat, bl, out, N);
}

// Round 6
// 129.111 us; speedup vs baseline: 2.9285x; 1.3221x over previous
//
#include <hip/hip_runtime.h>
#include <hip/hip_bf16.h>

#define IN_C 128
#define OUT_CH 128

typedef __attribute__((ext_vector_type(8))) short bf16x8;   // 8 bf16 = 4 VGPRs
typedef __attribute__((ext_vector_type(4))) float f32x4;

__device__ __forceinline__ unsigned pk2(float a, float b) {
    union { __hip_bfloat162 h; unsigned u; } c;
    c.h = __float22bfloat162_rn(make_float2(a, b));
    return c.u;
}
__device__ __forceinline__ float blo(unsigned v) { return __uint_as_float(v << 16); }
__device__ __forceinline__ float bhi(unsigned v) { return __uint_as_float(v & 0xffff0000u); }

__device__ __forceinline__ void add8(float* a, const uint4 v) {
    a[0] += blo(v.x); a[1] += bhi(v.x);
    a[2] += blo(v.y); a[3] += bhi(v.y);
    a[4] += blo(v.z); a[5] += bhi(v.z);
    a[6] += blo(v.w); a[7] += bhi(v.w);
}

// ---------------- prep: bf16 x copy (+ zero row N) and Wcat = [Wl|Wr] bf16 ----------------

__global__ void k_prep(const float* __restrict__ x, const float* __restrict__ Wl,
                       const float* __restrict__ Wr, uint* __restrict__ xb,
                       unsigned short* __restrict__ Wcat, int N) {
    const int idx = blockIdx.x * 256 + threadIdx.x;
    const int t8 = (N + 1) * 16;           // 8-float chunks incl. zero row
    if (idx < t8) {
        uint4 o = make_uint4(0u, 0u, 0u, 0u);
        if (idx < N * 16) {
            const float4* p = reinterpret_cast<const float4*>(x + (size_t)idx * 8);
            const float4 v0 = p[0], v1 = p[1];
            o.x = pk2(v0.x, v0.y); o.y = pk2(v0.z, v0.w);
            o.z = pk2(v1.x, v1.y); o.w = pk2(v1.z, v1.w);
        }
        reinterpret_cast<uint4*>(xb)[idx] = o;
    } else if (idx < t8 + 128 * 256) {
        const int w = idx - t8;
        const int n = w >> 8, k = w & 255;
        const float v = (k < IN_C) ? Wl[n * IN_C + k] : Wr[n * IN_C + (k - IN_C)];
        union { __hip_bfloat16 h; unsigned short s; } c;
        c.h = __float2bfloat16(v);
        Wcat[w] = c.s;
    }
}

// ---------------- CSR build (padded to 4-edge groups) ----------------

__global__ void k_count_pos(const int* __restrict__ dst, int* __restrict__ cnt,
                            int* __restrict__ pos, int E) {
    int e = blockIdx.x * blockDim.x + threadIdx.x;
    if (e < E) pos[e] = atomicAdd(&cnt[dst[e]], 1);
}

__global__ void k_bsum(const int* __restrict__ cnt, int* __restrict__ bsum, int N) {
    int i = blockIdx.x * 256 + threadIdx.x;
    int v = (i < N) ? ((cnt[i] + 3) & ~3) : 0;     // padded count
    for (int d = 1; d < 64; d <<= 1) v += __shfl_xor(v, d);
    __shared__ int w4[4];
    if ((threadIdx.x & 63) == 0) w4[threadIdx.x >> 6] = v;
    __syncthreads();
    if (threadIdx.x == 0) bsum[blockIdx.x] = w4[0] + w4[1] + w4[2] + w4[3];
}

__global__ void k_bscan(int* __restrict__ bsum, int nb) {   // nb <= 256
    __shared__ int b[256];
    int t = threadIdx.x;
    int v = (t < nb) ? bsum[t] : 0;
    b[t] = v; __syncthreads();
    for (int d = 1; d < 256; d <<= 1) {
        int u = (t >= d) ? b[t - d] : 0;
        __syncthreads();
        b[t] += u;
        __syncthreads();
    }
    if (t < nb) bsum[t] = b[t] - v;   // exclusive
}

// padded exclusive offsets; also writes pad slots of ebuf -> N (zero row)
__global__ void k_offs(const int* __restrict__ cnt, const int* __restrict__ bsum,
                       int* __restrict__ offs, int* __restrict__ ebuf, int N) {
    __shared__ int b[256];
    int t = threadIdx.x, i = blockIdx.x * 256 + t;
    int c = (i < N) ? cnt[i] : 0;
    int v = (c + 3) & ~3;
    b[t] = v; __syncthreads();
    for (int d = 1; d < 256; d <<= 1) {
        int u = (t >= d) ? b[t - d] : 0;
        __syncthreads();
        b[t] += u;
        __syncthreads();
    }
    if (i < N) {
        const int o = bsum[blockIdx.x] + b[t] - v;
        offs[i] = o;
        for (int p = c; p < v; ++p) ebuf[o + p] = N;   // pad -> zero row
    }
}

__global__ void k_bucket(const int* __restrict__ src, const int* __restrict__ dst,
                         const int* __restrict__ pos, const int* __restrict__ offs,
                         int* __restrict__ ebuf, int E) {
    int e = blockIdx.x * blockDim.x + threadIdx.x;
    if (e < E) ebuf[offs[dst[e]] + pos[e]] = src[e];
}

// ---------------- fused gather-mean + MFMA GEMM + bias + L2 norm ----------------
// Block = 256 threads (4 waves), 16 nodes. Gather: one node per 16-lane group
// (4 nodes concurrently per wave); lane owns a 16 B chunk of the 256 B bf16 row;
// edge ids arrive as aligned int4 (4 edges/iter, pads hit zero row N) -> 4
// independent b128 row loads per iter, no shfl in the address path.
// GEMM: [mean|x](16x256) @ Wcat^T(256x128), mfma_f32_16x16x32_bf16, wave wv owns
// 32 output cols. Epilogue: bias, sum-of-squares reduce, normalize, store fp32.
template<bool BF16X>
__global__ __launch_bounds__(256) void k_sage(
        const float* __restrict__ x, const uint* __restrict__ xb,
        const int* __restrict__ ebuf, const int* __restrict__ offs,
        const int* __restrict__ cnt, const unsigned short* __restrict__ Wcat,
        const float* __restrict__ bl, float* __restrict__ out, int N) {
    __shared__ unsigned short feat[16][264];   // 528 B row: [0..255]=mean, [256..511]=x, +16 pad
    __shared__ float ssh[4][16];

    const int tid  = threadIdx.x;
    const int lane = tid & 63;
    const int wv   = tid >> 6;
    const int g    = lane >> 4;        // node group within wave
    const int cl   = lane & 15;        // 16 B chunk within row
    const int node0 = blockIdx.x * 16;
    const int nl   = wv * 4 + g;
    const int node = node0 + nl;

    // ---- gather ----
    float a[8];
#pragma unroll
    for (int i = 0; i < 8; ++i) a[i] = 0.f;
    int m = 0, off = 0;
    if (node < N) { off = offs[node]; m = cnt[node]; }

    if (BF16X) {
        const uint* rowb = xb + cl * 4;
        for (int j = 0; j < m; j += 4) {
            const int4 q = *reinterpret_cast<const int4*>(ebuf + off + j);   // 16B-aligned
            const uint4 v0 = *reinterpret_cast<const uint4*>(rowb + (size_t)q.x * 64);
            const uint4 v1 = *reinterpret_cast<const uint4*>(rowb + (size_t)q.y * 64);
            const uint4 v2 = *reinterpret_cast<const uint4*>(rowb + (size_t)q.z * 64);
            const uint4 v3 = *reinterpret_cast<const uint4*>(rowb + (size_t)q.w * 64);
            add8(a, v0); add8(a, v1); add8(a, v2); add8(a, v3);
        }
    } else {
        for (int j = 0; j < m; j += 4) {
            const int4 q = *reinterpret_cast<const int4*>(ebuf + off + j);
            const int qq[4] = {q.x, q.y, q.z, q.w};
#pragma unroll
            for (int t = 0; t < 4; ++t) {
                if (j + t < m) {
                    const float4* pr = reinterpret_cast<const float4*>(
                        x + (size_t)qq[t] * IN_C + cl * 8);
                    const float4 u0 = pr[0], u1 = pr[1];
                    a[0] += u0.x; a[1] += u0.y; a[2] += u0.z; a[3] += u0.w;
                    a[4] += u1.x; a[5] += u1.y; a[6] += u1.z; a[7] += u1.w;
                }
            }
        }
    }
    const float inv = 1.0f / fmaxf((float)m, 1.0f);
    uint4 pw;
    pw.x = pk2(a[0] * inv, a[1] * inv); pw.y = pk2(a[2] * inv, a[3] * inv);
    pw.z = pk2(a[4] * inv, a[5] * inv); pw.w = pk2(a[6] * inv, a[7] * inv);
    char* frow = reinterpret_cast<char*>(&feat[nl][0]);
    *reinterpret_cast<uint4*>(frow + cl * 16) = pw;

    uint4 xr = make_uint4(0u, 0u, 0u, 0u);
    if (node < N) {
        if (BF16X) {
            xr = *reinterpret_cast<const uint4*>(xb + (size_t)node * 64 + cl * 4);
        } else {
            const float4* pr = reinterpret_cast<const float4*>(
                x + (size_t)node * IN_C + cl * 8);
            const float4 u0 = pr[0], u1 = pr[1];
            xr.x = pk2(u0.x, u0.y); xr.y = pk2(u0.z, u0.w);
            xr.z = pk2(u1.x, u1.y); xr.w = pk2(u1.z, u1.w);
        }
    }
    *reinterpret_cast<uint4*>(frow + 256 + cl * 16) = xr;
    __syncthreads();

    // ---- MFMA: 16 nodes x 128 cols, K=256; wave wv -> cols [wv*32, wv*32+32) ----
    const int m_lane = lane & 15;
    const int kq = lane >> 4;
    f32x4 acc[2] = {{0, 0, 0, 0}, {0, 0, 0, 0}};
    const char* arow  = reinterpret_cast<const char*>(&feat[m_lane][0]) + kq * 16;
    const char* bbase = reinterpret_cast<const char*>(Wcat)
                      + (size_t)(wv * 32 + m_lane) * 512 + kq * 16;
#pragma unroll
    for (int ks = 0; ks < 8; ++ks) {
        const bf16x8 af = *reinterpret_cast<const bf16x8*>(arow + ks * 64);
        const bf16x8 b0 = *reinterpret_cast<const bf16x8*>(bbase + ks * 64);
        const bf16x8 b1 = *reinterpret_cast<const bf16x8*>(bbase + 16 * 512 + ks * 64);
        acc[0] = __builtin_amdgcn_mfma_f32_16x16x32_bf16(af, b0, acc[0], 0, 0, 0);
        acc[1] = __builtin_amdgcn_mfma_f32_16x16x32_bf16(af, b1, acc[1], 0, 0, 0);
    }

    const float bb0 = bl[wv * 32 + m_lane];
    const float bb1 = bl[wv * 32 + 16 + m_lane];
#pragma unroll
    for (int r = 0; r < 4; ++r) { acc[0][r] += bb0; acc[1][r] += bb1; }

    // sum of squares: 16-lane tree (cols within wave), then across 4 waves via LDS
#pragma unroll
    for (int r = 0; r < 4; ++r) {
        float v = acc[0][r] * acc[0][r] + acc[1][r] * acc[1][r];
        v += __shfl_xor(v, 1); v += __shfl_xor(v, 2);
        v += __shfl_xor(v, 4); v += __shfl_xor(v, 8);
        if (m_lane == 0) ssh[wv][kq * 4 + r] = v;
    }
    __syncthreads();

#pragma unroll
    for (int r = 0; r < 4; ++r) {
        const int nn = kq * 4 + r;
        const int nd = node0 + nn;
        if (nd < N) {
            const float ss = ssh[0][nn] + ssh[1][nn] + ssh[2][nn] + ssh[3][nn];
            const float rn = 1.0f / fmaxf(sqrtf(ss), 1e-12f);
            out[(size_t)nd * OUT_CH + wv * 32 + m_lane]      = acc[0][r] * rn;
            out[(size_t)nd * OUT_CH + wv * 32 + 16 + m_lane] = acc[1][r] * rn;
        }
    }
}

extern "C" void kernel_launch(void* const* d_in, const int* in_sizes, int n_in,
                              void* d_out, int out_size, void* d_ws, size_t ws_size,
                              hipStream_t stream) {
    const float* x    = (const float*)d_in[0];
    const int*   edge = (const int*)d_in[1];
    const float* Wl   = (const float*)d_in[2];
    const float* bl   = (const float*)d_in[3];
    const float* Wr   = (const float*)d_in[4];
    float*       out  = (float*)d_out;

    const int N = in_sizes[0] / IN_C;
    const int E = in_sizes[1] / 2;
    const int* src = edge;
    const int* dst = edge + E;

    // ws: cnt[N] | offs[N] | bsum[256] | pos[E] | ebuf[E+3N+4] | Wcat[32K bf16] | xb[(N+1)*128 bf16]
    char* p = (char*)d_ws;
    int* cnt  = (int*)p;            p += (size_t)N * 4;
    int* offs = (int*)p;            p += (size_t)N * 4;
    int* bsum = (int*)p;            p += 256 * 4;
    int* pos  = (int*)p;            p += (size_t)E * 4;
    int* ebuf = (int*)p;            p += ((size_t)E + 3 * (size_t)N + 4) * 4;
    unsigned short* Wcat = (unsigned short*)p;  p += 128 * 256 * 2;
    const size_t base_bytes = (size_t)(p - (char*)d_ws);
    uint* xb = (uint*)p;
    const bool use_xb = ws_size >= base_bytes + ((size_t)N + 1) * IN_C * 2;

    hipMemsetAsync(cnt, 0, (size_t)N * 4, stream);

    const int prepN = (N + 1) * 16 + 128 * 256;
    k_prep<<<(prepN + 255) / 256, 256, 0, stream>>>(x, Wl, Wr, xb, Wcat, use_xb ? N : 0);

    const int blocksE = (E + 255) / 256;
    const int nb = (N + 255) / 256;
    k_count_pos<<<blocksE, 256, 0, stream>>>(dst, cnt, pos, E);
    k_bsum  <<<nb, 256, 0, stream>>>(cnt, bsum, N);
    k_bscan <<<1, 256, 0, stream>>>(bsum, nb);
    k_offs  <<<nb, 256, 0, stream>>>(cnt, bsum, offs, ebuf, N);
    k_bucket<<<blocksE, 256, 0, stream>>>(src, dst, pos, offs, ebuf, E);

    const int blocksN = (N + 15) / 16;
    if (use_xb)
        k_sage<true> <<<blocksN, 256, 0, stream>>>(x, xb, ebuf, offs, cnt, Wcat, bl, out, N);
    else
        k_sage<false><<<blocksN, 256, 0, stream>>>(x, xb, ebuf, offs, cnt, Wcat, bl, out, N);
}